// Round 1
// baseline (251.172 us; speedup 1.0000x reference)
//
#include <hip/hip_runtime.h>
#include <hip/hip_bf16.h>
#include <stdint.h>
#include <stddef.h>

#define NTOT 8192
#define BS   4096
#define DIM  1024

// ws layout (bytes)
#define OFF_TB      0u                    // bf16 total: 8192*1024*2 = 16777216
#define OFF_SQ      16777216u             // f32 [8192]
#define OFF_COLPART 16809984u             // f32 [64][1024]
#define OFF_BWP     17072128u             // f32 [8]
#define OFF_PART    17072192u             // f32 [4096]

typedef __attribute__((ext_vector_type(8))) short bf16x8;
typedef __attribute__((ext_vector_type(4))) float f32x4;

__device__ __forceinline__ unsigned short f2bf_rne(float f) {
  unsigned u = __float_as_uint(f);
  u += 0x7fffu + ((u >> 16) & 1u);
  return (unsigned short)(u >> 16);
}

__device__ __forceinline__ void load_lds16(const void* g, void* l) {
  __builtin_amdgcn_global_load_lds((const __attribute__((address_space(1))) void*)g,
                                   (__attribute__((address_space(3))) void*)l,
                                   16, 0, 0);
}

// ---- kernel A: bf16 convert + row sums of squares ----
__global__ __launch_bounds__(256) void prep_kernel(const float* __restrict__ src,
                                                   const float* __restrict__ tgt,
                                                   unsigned short* __restrict__ tb,
                                                   float* __restrict__ sq) {
  const int row = blockIdx.x;
  const int t = threadIdx.x;
  const float* base = (row < BS) ? (src + (size_t)row * DIM)
                                 : (tgt + (size_t)(row - BS) * DIM);
  float4 v = *reinterpret_cast<const float4*>(base + t * 4);
  ushort4 b;
  b.x = f2bf_rne(v.x); b.y = f2bf_rne(v.y);
  b.z = f2bf_rne(v.z); b.w = f2bf_rne(v.w);
  *reinterpret_cast<ushort4*>(tb + (size_t)row * DIM + t * 4) = b;
  float s = v.x*v.x + v.y*v.y + v.z*v.z + v.w*v.w;
  __shared__ float red[256];
  red[t] = s;
  __syncthreads();
  for (int off = 128; off > 0; off >>= 1) {
    if (t < off) red[t] += red[t + off];
    __syncthreads();
  }
  if (t == 0) sq[row] = red[0];
}

// ---- kernel B: per-block column-sum partials (deterministic, no atomics) ----
__global__ __launch_bounds__(256) void colsum_kernel(const float* __restrict__ src,
                                                     const float* __restrict__ tgt,
                                                     float* __restrict__ colpart) {
  const int g = blockIdx.x;   // 64 blocks, 128 rows each
  const int t = threadIdx.x;  // 4 cols per thread via float4
  float a0 = 0.f, a1 = 0.f, a2 = 0.f, a3 = 0.f;
  for (int r = 0; r < 128; ++r) {
    int row = g * 128 + r;
    const float* base = (row < BS) ? (src + (size_t)row * DIM)
                                   : (tgt + (size_t)(row - BS) * DIM);
    float4 v = *reinterpret_cast<const float4*>(base + t * 4);
    a0 += v.x; a1 += v.y; a2 += v.z; a3 += v.w;
  }
  float* o = colpart + (size_t)g * 1024 + t * 4;
  o[0] = a0; o[1] = a1; o[2] = a2; o[3] = a3;
}

// ---- kernel C: bandwidth from analytic sum(L2) ----
__global__ __launch_bounds__(256) void bw_kernel(const float* __restrict__ sq,
                                                 const float* __restrict__ colpart,
                                                 float* __restrict__ bwp) {
  const int t = threadIdx.x;
  double s1 = 0.0;
  for (int i = t; i < NTOT; i += 256) s1 += (double)sq[i];
  double s2 = 0.0;
  for (int c = t; c < 1024; c += 256) {
    float s = 0.f;
    for (int g = 0; g < 64; ++g) s += colpart[(size_t)g * 1024 + c];
    s2 += (double)s * (double)s;
  }
  __shared__ double r1[256], r2[256];
  r1[t] = s1; r2[t] = s2;
  __syncthreads();
  for (int off = 128; off > 0; off >>= 1) {
    if (t < off) { r1[t] += r1[t + off]; r2[t] += r2[t + off]; }
    __syncthreads();
  }
  if (t == 0) {
    const double n = (double)NTOT;
    double sumL2 = 2.0 * n * r1[0] - 2.0 * r2[0];
    double bw = sumL2 / (n * n - n);
    bw = bw / 4.0;  // KERNEL_MUL^(KERNEL_NUM//2) = 2^2
    for (int k = 0; k < 5; ++k)
      bwp[k] = (float)(-1.0 / (bw * (double)(1 << k)));
  }
}

// ---- kernel D: fused bf16 Gram GEMM + RBF epilogue + block reduction ----
// m97 structure: 128x128 tile, BK=32, 4 waves (2x2), 4x4 16x16x32 frags/wave.
__global__ __launch_bounds__(256) void mmd_gemm(const short* __restrict__ T,
                                                const float* __restrict__ sq,
                                                const float* __restrict__ bwp,
                                                float* __restrict__ partials) {
  __shared__ __align__(16) short sA[128 * 32];
  __shared__ __align__(16) short sB[128 * 32];
  __shared__ float red[256];

  const int tid  = threadIdx.x;
  const int lane = tid & 63;
  const int wave = tid >> 6;       // 0..3
  const int wr   = wave >> 1;      // wave row (0..1)
  const int wc   = wave & 1;       // wave col (0..1)
  const int bi   = blockIdx.x;     // row tile (0..63)
  const int bj   = blockIdx.y;     // col tile (0..63)

  const int f0 = tid;              // staging flat idx, issue 0
  const int f1 = 256 + tid;        // issue 1
  const size_t arow = (size_t)bi * 128;
  const size_t brow = (size_t)bj * 128;

  f32x4 acc[4][4] = {};

  const int r15 = lane & 15;
  const int kg  = lane >> 4;       // 0..3

  for (int k0 = 0; k0 < DIM; k0 += 32) {
    // stage A,B tiles: 128 rows x 32 k, 16B/lane, linear LDS dest
    load_lds16(T + (arow + (f0 >> 2)) * DIM + k0 + (f0 & 3) * 8,
               &sA[(size_t)(wave * 64) * 8]);
    load_lds16(T + (arow + (f1 >> 2)) * DIM + k0 + (f1 & 3) * 8,
               &sA[(size_t)(256 + wave * 64) * 8]);
    load_lds16(T + (brow + (f0 >> 2)) * DIM + k0 + (f0 & 3) * 8,
               &sB[(size_t)(wave * 64) * 8]);
    load_lds16(T + (brow + (f1 >> 2)) * DIM + k0 + (f1 & 3) * 8,
               &sB[(size_t)(256 + wave * 64) * 8]);
    __syncthreads();

    bf16x8 a[4], b[4];
#pragma unroll
    for (int m = 0; m < 4; ++m)
      a[m] = *reinterpret_cast<const bf16x8*>(&sA[(wr * 64 + m * 16 + r15) * 32 + kg * 8]);
#pragma unroll
    for (int n = 0; n < 4; ++n)
      b[n] = *reinterpret_cast<const bf16x8*>(&sB[(wc * 64 + n * 16 + r15) * 32 + kg * 8]);

#pragma unroll
    for (int m = 0; m < 4; ++m)
#pragma unroll
      for (int n = 0; n < 4; ++n)
        acc[m][n] = __builtin_amdgcn_mfma_f32_16x16x32_bf16(a[m], b[n], acc[m][n], 0, 0, 0);
    __syncthreads();
  }

  // epilogue: L2 -> multi-bandwidth exp -> per-thread sum
  const float ni0 = bwp[0], ni1 = bwp[1], ni2 = bwp[2], ni3 = bwp[3], ni4 = bwp[4];
  const int hi = lane >> 4;

  float sqi[4][4];
#pragma unroll
  for (int m = 0; m < 4; ++m)
#pragma unroll
    for (int r = 0; r < 4; ++r)
      sqi[m][r] = sq[bi * 128 + wr * 64 + m * 16 + hi * 4 + r];

  float tsum = 0.f;
#pragma unroll
  for (int n = 0; n < 4; ++n) {
    const float sqj = sq[bj * 128 + wc * 64 + n * 16 + r15];
#pragma unroll
    for (int m = 0; m < 4; ++m) {
#pragma unroll
      for (int r = 0; r < 4; ++r) {
        float l2 = sqi[m][r] + sqj - 2.f * acc[m][n][r];
        tsum += __expf(l2 * ni0) + __expf(l2 * ni1) + __expf(l2 * ni2)
              + __expf(l2 * ni3) + __expf(l2 * ni4);
      }
    }
  }

  red[tid] = tsum;
  __syncthreads();
  for (int off = 128; off > 0; off >>= 1) {
    if (tid < off) red[tid] += red[tid + off];
    __syncthreads();
  }
  if (tid == 0) {
    float sign = ((bi < 32) == (bj < 32)) ? 1.f : -1.f;
    partials[bj * 64 + bi] = sign * red[0];
  }
}

// ---- kernel E: final reduction ----
__global__ __launch_bounds__(256) void finish_kernel(const float* __restrict__ partials,
                                                     float* __restrict__ out) {
  const int t = threadIdx.x;
  double s = 0.0;
  for (int i = t; i < 4096; i += 256) s += (double)partials[i];
  __shared__ double rd[256];
  rd[t] = s;
  __syncthreads();
  for (int off = 128; off > 0; off >>= 1) {
    if (t < off) rd[t] += rd[t + off];
    __syncthreads();
  }
  if (t == 0) out[0] = (float)(rd[0] / 16777216.0);  // / bs^2
}

extern "C" void kernel_launch(void* const* d_in, const int* in_sizes, int n_in,
                              void* d_out, int out_size, void* d_ws, size_t ws_size,
                              hipStream_t stream) {
  const float* src = (const float*)d_in[0];
  const float* tgt = (const float*)d_in[1];
  char* ws = (char*)d_ws;
  unsigned short* tb = (unsigned short*)(ws + OFF_TB);
  float* sq       = (float*)(ws + OFF_SQ);
  float* colpart  = (float*)(ws + OFF_COLPART);
  float* bwp      = (float*)(ws + OFF_BWP);
  float* partials = (float*)(ws + OFF_PART);

  prep_kernel<<<dim3(NTOT), dim3(256), 0, stream>>>(src, tgt, tb, sq);
  colsum_kernel<<<dim3(64), dim3(256), 0, stream>>>(src, tgt, colpart);
  bw_kernel<<<dim3(1), dim3(256), 0, stream>>>(sq, colpart, bwp);
  mmd_gemm<<<dim3(64, 64), dim3(256), 0, stream>>>((const short*)tb, sq, bwp, partials);
  finish_kernel<<<dim3(1), dim3(256), 0, stream>>>(partials, (float*)d_out);
}

// Round 2
// 182.022 us; speedup vs baseline: 1.3799x; 1.3799x over previous
//
#include <hip/hip_runtime.h>
#include <hip/hip_bf16.h>
#include <stdint.h>
#include <stddef.h>

#define NTOT 8192
#define BS   4096
#define DIM  1024
#define NTRI 2080   // 64*65/2 triangular tiles

// ws layout (bytes)
#define OFF_TB      0u                    // bf16 total: 8192*1024*2 = 16777216
#define OFF_SQ      16777216u             // f32 [8192]
#define OFF_COLPART 16809984u             // f32 [64][1024]
#define OFF_BWP     17072128u             // f32 [8]
#define OFF_PART    17072192u             // f32 [NTRI]

typedef __attribute__((ext_vector_type(8))) short bf16x8;
typedef __attribute__((ext_vector_type(4))) float f32x4;

__device__ __forceinline__ unsigned short f2bf_rne(float f) {
  unsigned u = __float_as_uint(f);
  u += 0x7fffu + ((u >> 16) & 1u);
  return (unsigned short)(u >> 16);
}

__device__ __forceinline__ void load_lds16(const void* g, void* l) {
  __builtin_amdgcn_global_load_lds((const __attribute__((address_space(1))) void*)g,
                                   (__attribute__((address_space(3))) void*)l,
                                   16, 0, 0);
}

// ---- kernel A: bf16 convert + row sums of squares ----
__global__ __launch_bounds__(256) void prep_kernel(const float* __restrict__ src,
                                                   const float* __restrict__ tgt,
                                                   unsigned short* __restrict__ tb,
                                                   float* __restrict__ sq) {
  const int row = blockIdx.x;
  const int t = threadIdx.x;
  const float* base = (row < BS) ? (src + (size_t)row * DIM)
                                 : (tgt + (size_t)(row - BS) * DIM);
  float4 v = *reinterpret_cast<const float4*>(base + t * 4);
  ushort4 b;
  b.x = f2bf_rne(v.x); b.y = f2bf_rne(v.y);
  b.z = f2bf_rne(v.z); b.w = f2bf_rne(v.w);
  *reinterpret_cast<ushort4*>(tb + (size_t)row * DIM + t * 4) = b;
  float s = v.x*v.x + v.y*v.y + v.z*v.z + v.w*v.w;
  __shared__ float red[256];
  red[t] = s;
  __syncthreads();
  for (int off = 128; off > 0; off >>= 1) {
    if (t < off) red[t] += red[t + off];
    __syncthreads();
  }
  if (t == 0) sq[row] = red[0];
}

// ---- kernel B: per-block column-sum partials (deterministic, no atomics) ----
__global__ __launch_bounds__(256) void colsum_kernel(const float* __restrict__ src,
                                                     const float* __restrict__ tgt,
                                                     float* __restrict__ colpart) {
  const int g = blockIdx.x;   // 64 blocks, 128 rows each
  const int t = threadIdx.x;  // 4 cols per thread via float4
  float a0 = 0.f, a1 = 0.f, a2 = 0.f, a3 = 0.f;
  for (int r = 0; r < 128; ++r) {
    int row = g * 128 + r;
    const float* base = (row < BS) ? (src + (size_t)row * DIM)
                                   : (tgt + (size_t)(row - BS) * DIM);
    float4 v = *reinterpret_cast<const float4*>(base + t * 4);
    a0 += v.x; a1 += v.y; a2 += v.z; a3 += v.w;
  }
  float* o = colpart + (size_t)g * 1024 + t * 4;
  o[0] = a0; o[1] = a1; o[2] = a2; o[3] = a3;
}

// ---- kernel C: bandwidth from analytic sum(L2) ----
__global__ __launch_bounds__(256) void bw_kernel(const float* __restrict__ sq,
                                                 const float* __restrict__ colpart,
                                                 float* __restrict__ bwp) {
  const int t = threadIdx.x;
  double s1 = 0.0;
  for (int i = t; i < NTOT; i += 256) s1 += (double)sq[i];
  double s2 = 0.0;
  for (int c = t; c < 1024; c += 256) {
    float s = 0.f;
    for (int g = 0; g < 64; ++g) s += colpart[(size_t)g * 1024 + c];
    s2 += (double)s * (double)s;
  }
  __shared__ double r1[256], r2[256];
  r1[t] = s1; r2[t] = s2;
  __syncthreads();
  for (int off = 128; off > 0; off >>= 1) {
    if (t < off) { r1[t] += r1[t + off]; r2[t] += r2[t + off]; }
    __syncthreads();
  }
  if (t == 0) {
    const double n = (double)NTOT;
    double sumL2 = 2.0 * n * r1[0] - 2.0 * r2[0];
    double bw = sumL2 / (n * n - n);
    bw = bw / 4.0;  // KERNEL_MUL^(KERNEL_NUM//2) = 2^2
    for (int k = 0; k < 5; ++k)
      bwp[k] = (float)(-1.0 / (bw * (double)(1 << k)));
  }
}

// ---- kernel D: fused bf16 Gram GEMM + RBF epilogue, upper-triangular tiles ----
// m97 structure: 128x128 tile, BK=32, 4 waves (2x2), 4x4 16x16x32 frags/wave.
// K(i,j)=K(j,i) bit-exactly (same fragments, same pairings), so only tiles
// bi<=bj are computed; off-diagonal tiles carry weight 2.
__global__ __launch_bounds__(256) void mmd_gemm(const short* __restrict__ T,
                                                const float* __restrict__ sq,
                                                const float* __restrict__ bwp,
                                                float* __restrict__ partials) {
  __shared__ __align__(16) short sA[128 * 32];
  __shared__ __align__(16) short sB[128 * 32];
  __shared__ float red[256];

  const int tid  = threadIdx.x;
  const int lane = tid & 63;
  const int wave = tid >> 6;       // 0..3
  const int wr   = wave >> 1;      // wave row (0..1)
  const int wc   = wave & 1;       // wave col (0..1)

  // triangular decode: tile t -> (bi, bj) with bi<=bj, f(bi)=bi*(129-bi)/2
  const int tno = blockIdx.x;
  int bi = (int)((129.0f - sqrtf(129.0f * 129.0f - 8.0f * (float)tno)) * 0.5f);
  while (bi > 0 && bi * (129 - bi) / 2 > tno) --bi;
  while ((bi + 1) * (129 - (bi + 1)) / 2 <= tno) ++bi;
  const int bj = bi + (tno - bi * (129 - bi) / 2);

  const int f0 = tid;              // staging flat idx, issue 0
  const int f1 = 256 + tid;        // issue 1
  const size_t arow = (size_t)bi * 128;
  const size_t brow = (size_t)bj * 128;

  f32x4 acc[4][4] = {};

  const int r15 = lane & 15;
  const int kg  = lane >> 4;       // 0..3

  for (int k0 = 0; k0 < DIM; k0 += 32) {
    // stage A,B tiles: 128 rows x 32 k, 16B/lane, linear LDS dest
    load_lds16(T + (arow + (f0 >> 2)) * DIM + k0 + (f0 & 3) * 8,
               &sA[(size_t)(wave * 64) * 8]);
    load_lds16(T + (arow + (f1 >> 2)) * DIM + k0 + (f1 & 3) * 8,
               &sA[(size_t)(256 + wave * 64) * 8]);
    load_lds16(T + (brow + (f0 >> 2)) * DIM + k0 + (f0 & 3) * 8,
               &sB[(size_t)(wave * 64) * 8]);
    load_lds16(T + (brow + (f1 >> 2)) * DIM + k0 + (f1 & 3) * 8,
               &sB[(size_t)(256 + wave * 64) * 8]);
    __syncthreads();

    bf16x8 a[4], b[4];
#pragma unroll
    for (int m = 0; m < 4; ++m)
      a[m] = *reinterpret_cast<const bf16x8*>(&sA[(wr * 64 + m * 16 + r15) * 32 + kg * 8]);
#pragma unroll
    for (int n = 0; n < 4; ++n)
      b[n] = *reinterpret_cast<const bf16x8*>(&sB[(wc * 64 + n * 16 + r15) * 32 + kg * 8]);

#pragma unroll
    for (int m = 0; m < 4; ++m)
#pragma unroll
      for (int n = 0; n < 4; ++n)
        acc[m][n] = __builtin_amdgcn_mfma_f32_16x16x32_bf16(a[m], b[n], acc[m][n], 0, 0, 0);
    __syncthreads();
  }

  // epilogue: L2 -> multi-bandwidth exp (geometric ladder => sqrt chain)
  const float ni0 = bwp[0];
  const int hi = lane >> 4;

  float sqi[4][4];
#pragma unroll
  for (int m = 0; m < 4; ++m)
#pragma unroll
    for (int r = 0; r < 4; ++r)
      sqi[m][r] = sq[bi * 128 + wr * 64 + m * 16 + hi * 4 + r];

  float tsum = 0.f;
#pragma unroll
  for (int n = 0; n < 4; ++n) {
    const float sqj = sq[bj * 128 + wc * 64 + n * 16 + r15];
#pragma unroll
    for (int m = 0; m < 4; ++m) {
#pragma unroll
      for (int r = 0; r < 4; ++r) {
        float l2 = sqi[m][r] + sqj - 2.f * acc[m][n][r];
        // e_k = exp(l2*ni0/2^k) = sqrt(e_{k-1}); l2*ni0 ~ -4, no underflow
        float e0 = __expf(l2 * ni0);
        float e1 = sqrtf(e0);
        float e2 = sqrtf(e1);
        float e3 = sqrtf(e2);
        float e4 = sqrtf(e3);
        tsum += e0 + e1 + e2 + e3 + e4;
      }
    }
  }

  red[tid] = tsum;
  __syncthreads();
  for (int off = 128; off > 0; off >>= 1) {
    if (tid < off) red[tid] += red[tid + off];
    __syncthreads();
  }
  if (tid == 0) {
    float sign = ((bi < 32) == (bj < 32)) ? 1.f : -1.f;
    float w    = (bi == bj) ? 1.f : 2.f;
    partials[tno] = sign * w * red[0];
  }
}

// ---- kernel E: final reduction ----
__global__ __launch_bounds__(256) void finish_kernel(const float* __restrict__ partials,
                                                     float* __restrict__ out) {
  const int t = threadIdx.x;
  double s = 0.0;
  for (int i = t; i < NTRI; i += 256) s += (double)partials[i];
  __shared__ double rd[256];
  rd[t] = s;
  __syncthreads();
  for (int off = 128; off > 0; off >>= 1) {
    if (t < off) rd[t] += rd[t + off];
    __syncthreads();
  }
  if (t == 0) out[0] = (float)(rd[0] / 16777216.0);  // / bs^2
}

extern "C" void kernel_launch(void* const* d_in, const int* in_sizes, int n_in,
                              void* d_out, int out_size, void* d_ws, size_t ws_size,
                              hipStream_t stream) {
  const float* src = (const float*)d_in[0];
  const float* tgt = (const float*)d_in[1];
  char* ws = (char*)d_ws;
  unsigned short* tb = (unsigned short*)(ws + OFF_TB);
  float* sq       = (float*)(ws + OFF_SQ);
  float* colpart  = (float*)(ws + OFF_COLPART);
  float* bwp      = (float*)(ws + OFF_BWP);
  float* partials = (float*)(ws + OFF_PART);

  prep_kernel<<<dim3(NTOT), dim3(256), 0, stream>>>(src, tgt, tb, sq);
  colsum_kernel<<<dim3(64), dim3(256), 0, stream>>>(src, tgt, colpart);
  bw_kernel<<<dim3(1), dim3(256), 0, stream>>>(sq, colpart, bwp);
  mmd_gemm<<<dim3(NTRI), dim3(256), 0, stream>>>((const short*)tb, sq, bwp, partials);
  finish_kernel<<<dim3(1), dim3(256), 0, stream>>>(partials, (float*)d_out);
}

// Round 3
// 148.880 us; speedup vs baseline: 1.6871x; 1.2226x over previous
//
#include <hip/hip_runtime.h>
#include <hip/hip_bf16.h>
#include <stdint.h>
#include <stddef.h>

#define NTOT 8192
#define BS   4096
#define DIM  1024
#define NTRI 2080   // 64*65/2 triangular tiles

// ws layout (bytes)
#define OFF_TB      0u          // bf16 total: 8192*1024*2 = 16777216
#define OFF_SQ      16777216u   // f32 [8192]
#define OFF_COLPART 16809984u   // f32 [128][1024]
#define OFF_BWP     17334272u   // f32 [8]
#define OFF_PART    17334336u   // f32 [NTRI]

typedef __attribute__((ext_vector_type(8))) short bf16x8;
typedef __attribute__((ext_vector_type(4))) float f32x4;

__device__ __forceinline__ unsigned short f2bf_rne(float f) {
  unsigned u = __float_as_uint(f);
  u += 0x7fffu + ((u >> 16) & 1u);
  return (unsigned short)(u >> 16);
}

__device__ __forceinline__ float bf2f(unsigned short h) {
  return __uint_as_float((unsigned)h << 16);
}

__device__ __forceinline__ float fast_sqrt(float x) {
#if __has_builtin(__builtin_amdgcn_sqrtf)
  return __builtin_amdgcn_sqrtf(x);
#else
  float r; asm("v_sqrt_f32 %0, %1" : "=v"(r) : "v"(x)); return r;
#endif
}

__device__ __forceinline__ float fast_exp2(float x) {
#if __has_builtin(__builtin_amdgcn_exp2f)
  return __builtin_amdgcn_exp2f(x);
#else
  float r; asm("v_exp_f32 %0, %1" : "=v"(r) : "v"(x)); return r;
#endif
}

__device__ __forceinline__ void load_lds16(const void* g, void* l) {
  __builtin_amdgcn_global_load_lds((const __attribute__((address_space(1))) void*)g,
                                   (__attribute__((address_space(3))) void*)l,
                                   16, 0, 0);
}

// ---- kernel A: bf16 convert + row sums of squares (16 rows/block) ----
__global__ __launch_bounds__(256) void prep_kernel(const float* __restrict__ src,
                                                   const float* __restrict__ tgt,
                                                   unsigned short* __restrict__ tb,
                                                   float* __restrict__ sq) {
  const int t = threadIdx.x;
  const int lane = t & 63, wave = t >> 6;
  const int r0 = blockIdx.x * 16;
  __shared__ float rs[16][4];
#pragma unroll 4
  for (int r = 0; r < 16; ++r) {
    const int row = r0 + r;
    const float* base = (row < BS) ? (src + (size_t)row * DIM)
                                   : (tgt + (size_t)(row - BS) * DIM);
    float4 v = *reinterpret_cast<const float4*>(base + t * 4);
    ushort4 b;
    b.x = f2bf_rne(v.x); b.y = f2bf_rne(v.y);
    b.z = f2bf_rne(v.z); b.w = f2bf_rne(v.w);
    *reinterpret_cast<ushort4*>(tb + (size_t)row * DIM + t * 4) = b;
    float s = v.x*v.x + v.y*v.y + v.z*v.z + v.w*v.w;
#pragma unroll
    for (int off = 32; off > 0; off >>= 1) s += __shfl_down(s, off, 64);
    if (lane == 0) rs[r][wave] = s;
  }
  __syncthreads();
  if (t < 16) sq[r0 + t] = (rs[t][0] + rs[t][1]) + (rs[t][2] + rs[t][3]);
}

// ---- kernel B: column-sum partials from the cache-hot bf16 copy ----
// (s2 term is ~5 orders below the dominant term of sum(L2); bf16 rounding
//  of the colsums is harmless to bw.)
__global__ __launch_bounds__(256) void colsum_kernel(const unsigned short* __restrict__ tb,
                                                     float* __restrict__ colpart) {
  const int g = blockIdx.x;   // 128 blocks, 64 rows each
  const int t = threadIdx.x;  // 4 cols per thread
  float a0 = 0.f, a1 = 0.f, a2 = 0.f, a3 = 0.f;
  for (int r = 0; r < 64; ++r) {
    const int row = g * 64 + r;
    ushort4 u = *reinterpret_cast<const ushort4*>(tb + (size_t)row * DIM + t * 4);
    a0 += bf2f(u.x); a1 += bf2f(u.y); a2 += bf2f(u.z); a3 += bf2f(u.w);
  }
  float4 o = {a0, a1, a2, a3};
  *reinterpret_cast<float4*>(colpart + (size_t)g * 1024 + t * 4) = o;
}

// ---- kernel C: bandwidth from analytic sum(L2) ----
__global__ __launch_bounds__(256) void bw_kernel(const float* __restrict__ sq,
                                                 const float* __restrict__ colpart,
                                                 float* __restrict__ bwp) {
  const int t = threadIdx.x;
  double s1 = 0.0;
  for (int i = t; i < NTOT; i += 256) s1 += (double)sq[i];
  double s2 = 0.0;
  for (int c = t; c < 1024; c += 256) {
    float s = 0.f;
    for (int g = 0; g < 128; ++g) s += colpart[(size_t)g * 1024 + c];
    s2 += (double)s * (double)s;
  }
  __shared__ double r1[256], r2[256];
  r1[t] = s1; r2[t] = s2;
  __syncthreads();
  for (int off = 128; off > 0; off >>= 1) {
    if (t < off) { r1[t] += r1[t + off]; r2[t] += r2[t + off]; }
    __syncthreads();
  }
  if (t == 0) {
    const double n = (double)NTOT;
    double sumL2 = 2.0 * n * r1[0] - 2.0 * r2[0];
    double bw = sumL2 / (n * n - n);
    bw = bw / 4.0;  // KERNEL_MUL^(KERNEL_NUM//2) = 2^2
    const double LOG2E = 1.4426950408889634;
    for (int k = 0; k < 5; ++k)
      bwp[k] = (float)(-LOG2E / (bw * (double)(1 << k)));  // exp2-folded
  }
}

// ---- kernel D: fused bf16 Gram GEMM + RBF epilogue, upper-triangular tiles ----
// m97 structure: 128x128 tile, BK=32, 4 waves (2x2), 4x4 16x16x32 frags/wave.
// K(i,j)=K(j,i) bit-exactly (same fragments, same pairings) -> only bi<=bj,
// off-diagonal tiles weighted 2. XCD-chunked tile order (2080 = 8*260).
__global__ __launch_bounds__(256) void mmd_gemm(const short* __restrict__ T,
                                                const float* __restrict__ sq,
                                                const float* __restrict__ bwp,
                                                float* __restrict__ partials) {
  __shared__ __align__(16) short sA[128 * 32];
  __shared__ __align__(16) short sB[128 * 32];
  __shared__ float wred[4];

  const int tid  = threadIdx.x;
  const int lane = tid & 63;
  const int wave = tid >> 6;       // 0..3
  const int wr   = wave >> 1;      // wave row (0..1)
  const int wc   = wave & 1;       // wave col (0..1)

  // XCD-aware chunked swizzle: 8 XCDs x 260 contiguous triangular tiles
  const int tno = (blockIdx.x & 7) * 260 + (blockIdx.x >> 3);
  // triangular decode: tile tno -> (bi, bj) with bi<=bj, f(bi)=bi*(129-bi)/2
  int bi = (int)((129.0f - fast_sqrt(129.0f * 129.0f - 8.0f * (float)tno)) * 0.5f);
  while (bi > 0 && bi * (129 - bi) / 2 > tno) --bi;
  while ((bi + 1) * (129 - (bi + 1)) / 2 <= tno) ++bi;
  const int bj = bi + (tno - bi * (129 - bi) / 2);

  const int f0 = tid;              // staging flat idx, issue 0
  const int f1 = 256 + tid;        // issue 1
  const size_t arow = (size_t)bi * 128;
  const size_t brow = (size_t)bj * 128;

  f32x4 acc[4][4] = {};

  const int r15 = lane & 15;
  const int kg  = lane >> 4;       // 0..3

  for (int k0 = 0; k0 < DIM; k0 += 32) {
    // stage A,B tiles: 128 rows x 32 k, 16B/lane, linear LDS dest
    load_lds16(T + (arow + (f0 >> 2)) * DIM + k0 + (f0 & 3) * 8,
               &sA[(size_t)(wave * 64) * 8]);
    load_lds16(T + (arow + (f1 >> 2)) * DIM + k0 + (f1 & 3) * 8,
               &sA[(size_t)(256 + wave * 64) * 8]);
    load_lds16(T + (brow + (f0 >> 2)) * DIM + k0 + (f0 & 3) * 8,
               &sB[(size_t)(wave * 64) * 8]);
    load_lds16(T + (brow + (f1 >> 2)) * DIM + k0 + (f1 & 3) * 8,
               &sB[(size_t)(256 + wave * 64) * 8]);
    __syncthreads();

    bf16x8 a[4], b[4];
#pragma unroll
    for (int m = 0; m < 4; ++m)
      a[m] = *reinterpret_cast<const bf16x8*>(&sA[(wr * 64 + m * 16 + r15) * 32 + kg * 8]);
#pragma unroll
    for (int n = 0; n < 4; ++n)
      b[n] = *reinterpret_cast<const bf16x8*>(&sB[(wc * 64 + n * 16 + r15) * 32 + kg * 8]);

#pragma unroll
    for (int m = 0; m < 4; ++m)
#pragma unroll
      for (int n = 0; n < 4; ++n)
        acc[m][n] = __builtin_amdgcn_mfma_f32_16x16x32_bf16(a[m], b[n], acc[m][n], 0, 0, 0);
    __syncthreads();
  }

  // epilogue: x = l2 * ni0 (exp2-domain); e_k = sqrt(e_{k-1})
  const float ni0 = bwp[0];          // = -log2e / bw
  const float c2  = -2.f * ni0;
  const int hi = lane >> 4;

  float ai[4][4];
#pragma unroll
  for (int m = 0; m < 4; ++m)
#pragma unroll
    for (int r = 0; r < 4; ++r)
      ai[m][r] = sq[bi * 128 + wr * 64 + m * 16 + hi * 4 + r] * ni0;

  float tsum = 0.f;
#pragma unroll
  for (int n = 0; n < 4; ++n) {
    const float bjv = sq[bj * 128 + wc * 64 + n * 16 + r15] * ni0;
#pragma unroll
    for (int m = 0; m < 4; ++m) {
#pragma unroll
      for (int r = 0; r < 4; ++r) {
        float x = fmaf(acc[m][n][r], c2, ai[m][r] + bjv);
        float e0 = fast_exp2(x);      // x ~ -6, no underflow anywhere in chain
        float e1 = fast_sqrt(e0);
        float e2 = fast_sqrt(e1);
        float e3 = fast_sqrt(e2);
        float e4 = fast_sqrt(e3);
        tsum += ((e0 + e1) + (e2 + e3)) + e4;
      }
    }
  }

#pragma unroll
  for (int off = 32; off > 0; off >>= 1) tsum += __shfl_down(tsum, off, 64);
  if (lane == 0) wred[wave] = tsum;
  __syncthreads();
  if (tid == 0) {
    float sign = ((bi < 32) == (bj < 32)) ? 1.f : -1.f;
    float w    = (bi == bj) ? 1.f : 2.f;
    partials[tno] = sign * w * ((wred[0] + wred[1]) + (wred[2] + wred[3]));
  }
}

// ---- kernel E: final reduction ----
__global__ __launch_bounds__(256) void finish_kernel(const float* __restrict__ partials,
                                                     float* __restrict__ out) {
  const int t = threadIdx.x;
  double s = 0.0;
  for (int i = t; i < NTRI; i += 256) s += (double)partials[i];
  __shared__ double rd[256];
  rd[t] = s;
  __syncthreads();
  for (int off = 128; off > 0; off >>= 1) {
    if (t < off) rd[t] += rd[t + off];
    __syncthreads();
  }
  if (t == 0) out[0] = (float)(rd[0] / 16777216.0);  // / bs^2
}

extern "C" void kernel_launch(void* const* d_in, const int* in_sizes, int n_in,
                              void* d_out, int out_size, void* d_ws, size_t ws_size,
                              hipStream_t stream) {
  const float* src = (const float*)d_in[0];
  const float* tgt = (const float*)d_in[1];
  char* ws = (char*)d_ws;
  unsigned short* tb = (unsigned short*)(ws + OFF_TB);
  float* sq       = (float*)(ws + OFF_SQ);
  float* colpart  = (float*)(ws + OFF_COLPART);
  float* bwp      = (float*)(ws + OFF_BWP);
  float* partials = (float*)(ws + OFF_PART);

  prep_kernel<<<dim3(512), dim3(256), 0, stream>>>(src, tgt, tb, sq);
  colsum_kernel<<<dim3(128), dim3(256), 0, stream>>>(tb, colpart);
  bw_kernel<<<dim3(1), dim3(256), 0, stream>>>(sq, colpart, bwp);
  mmd_gemm<<<dim3(NTRI), dim3(256), 0, stream>>>((const short*)tb, sq, bwp, partials);
  finish_kernel<<<dim3(1), dim3(256), 0, stream>>>(partials, (float*)d_out);
}